// Round 1
// baseline (556.371 us; speedup 1.0000x reference)
//
#include <hip/hip_runtime.h>
#include <hip/hip_bf16.h>

#define BSZ 4
#define SEQ 2048
#define DMODEL 1024
#define DINNER 2048
#define DSTATE 64
#define NH 32
#define HD 64
#define CKL 64            // chunk length
#define NCH 32            // chunks per sequence
#define CONVD 2176
#define DPROJ 4256
#define N1 4224           // GEMM1 N = DINNER + CONVD = 11*384 (dt cols handled separately)
#define MTOT 8192         // BSZ*SEQ
#define YSTR 72           // LDS row stride (bf16): 144 B, keeps 16B alignment

typedef __hip_bfloat16 bf16;
typedef __attribute__((ext_vector_type(8))) short short8;   // 8 bf16 (4 VGPRs)
typedef __attribute__((ext_vector_type(4))) short short4_;  // 8 bytes
typedef __attribute__((ext_vector_type(4))) float f32x4;

__device__ __forceinline__ float sigmoidf_(float x) { return 1.0f / (1.0f + __expf(-x)); }
__device__ __forceinline__ float bits2f(short s) { return __uint_as_float(((unsigned)(unsigned short)s) << 16); }
__device__ __forceinline__ short f2bits(float f) {
    bf16 h = __float2bfloat16(f);
    return *reinterpret_cast<short*>(&h);
}

__device__ __forceinline__ void gl_lds16(const bf16* g, bf16* l) {
    __builtin_amdgcn_global_load_lds((const __attribute__((address_space(1))) void*)g,
                                     (__attribute__((address_space(3))) void*)l, 16, 0, 0);
}

__device__ __forceinline__ f32x4 MF(short8 a, short8 b, f32x4 c) {
    return __builtin_amdgcn_mfma_f32_16x16x32_bf16(a, b, c, 0, 0, 0);
}

// counted s_waitcnt vmcnt(N) with "memory" clobber: acts as a compiler memory
// fence so next-phase ds_reads can't hoist above the synchronization point.
template<int N> __device__ __forceinline__ void vmw() {
    if constexpr (N < 0) {}
    else if constexpr (N == 0)  asm volatile("s_waitcnt vmcnt(0)" ::: "memory");
    else if constexpr (N == 1)  asm volatile("s_waitcnt vmcnt(1)" ::: "memory");
    else if constexpr (N == 2)  asm volatile("s_waitcnt vmcnt(2)" ::: "memory");
    else if constexpr (N == 3)  asm volatile("s_waitcnt vmcnt(3)" ::: "memory");
    else if constexpr (N == 4)  asm volatile("s_waitcnt vmcnt(4)" ::: "memory");
    else if constexpr (N == 5)  asm volatile("s_waitcnt vmcnt(5)" ::: "memory");
    else if constexpr (N == 6)  asm volatile("s_waitcnt vmcnt(6)" ::: "memory");
    else if constexpr (N == 7)  asm volatile("s_waitcnt vmcnt(7)" ::: "memory");
    else if constexpr (N == 8)  asm volatile("s_waitcnt vmcnt(8)" ::: "memory");
    else if constexpr (N == 9)  asm volatile("s_waitcnt vmcnt(9)" ::: "memory");
    else if constexpr (N == 10) asm volatile("s_waitcnt vmcnt(10)" ::: "memory");
    else if constexpr (N == 11) asm volatile("s_waitcnt vmcnt(11)" ::: "memory");
    else if constexpr (N == 12) asm volatile("s_waitcnt vmcnt(12)" ::: "memory");
    else                        asm volatile("s_waitcnt vmcnt(15)" ::: "memory");
}

// ---------------- both weight converts in one launch ----------------
__global__ void k_cvt2(const float* __restrict__ W_in, const float* __restrict__ W_out,
                       const float* __restrict__ nw, bf16* __restrict__ win_b,
                       bf16* __restrict__ wout_b) {
    int g = (blockIdx.x * 256 + threadIdx.x) * 4;
    if (g < N1 * DMODEL) {
        f32x4 f = *(const f32x4*)&W_in[g];
        short4_ o;
#pragma unroll
        for (int j = 0; j < 4; j++) o[j] = f2bits(f[j]);
        *(short4_*)&win_b[g] = o;
    } else if (g < N1 * DMODEL + DMODEL * DINNER) {
        int g2 = g - N1 * DMODEL;
        f32x4 f = *(const f32x4*)&W_out[g2];
        f32x4 w = *(const f32x4*)&nw[g2 & (DINNER - 1)];
        short4_ o;
#pragma unroll
        for (int j = 0; j < 4; j++) o[j] = f2bits(f[j] * w[j]);
        *(short4_*)&wout_b[g2] = o;
    }
}

// =====================================================================
// 8-wave, 4-phase/K-tile GEMM with counted-vmcnt deep pipeline (T2+T3+T4+T5).
// C[M][N] = A[M][K] * W[N][K]^T, tiles BM=128 x BN, BK=64.
// Waves 2M x 4N, per-wave output 64 x (BN/4). K-tile split into k-lo/k-hi
// 32-col halves stored as SEPARATE contiguous LDS arrays so each half is a
// linear global_load_lds target (half-tile = stage unit).
//
// LDS read swizzle (conflict-free, 8 slots x 2 lanes per 16-lane group):
//   row r stored at line pi(r) = swap bits0<->2 of r; within a 64B line the
//   16B chunk c holds global chunk c ^ (r&3). Staged by pre-swizzling the
//   per-lane GLOBAL source address (LDS dest stays linear).
//
// Pipeline (per K-tile t, buffer d = t&1), stages issued off critical path:
//   P0: read B klo (NJ) + A frags0,1 klo | stage A-khi(t+1)->d^1 | 2*NJ mfma
//   P1: read A frags2,3 klo              | stage B-klo(t+2)->d   | 2*NJ mfma
//   P2: read B khi + A frags0,1 khi      | stage A-klo(t+2)->d   | 2*NJ mfma
//   P3: read A frags2,3 khi              | stage B-khi(t+2)->d   | 2*NJ mfma
// Waits (LB = loads/thread per B half-stage, A half = 1 load):
//   steady  : vmcnt(3*LB+2) at P1-end (guards P2's A-khi/B-khi reads) and at
//             P3-end (guards next tile's P0 klo reads)
//   t==NT-2 : vmcnt(2*LB+2) at P1-end, vmcnt(LB+1) at P3-end
//   t==NT-1 : vmcnt(0) at P1-end (final drain), none at P3-end
// Region-reuse safety: a stage only writes a region whose last reads finished
// in an earlier phase (>=1 s_barrier before the issue); readers of staged data
// sit after the staging wave's vmcnt + an s_barrier.
// =====================================================================
template<int BN, int NT, int LDA, int LDC, bool RMS, typename CT>
__global__ __launch_bounds__(512, 2) void k_mm8(const bf16* __restrict__ Ap,
                                                const bf16* __restrict__ Wp,
                                                CT* __restrict__ Cp) {
    constexpr int K   = NT * 64;
    constexpr int NJ  = BN / 64;    // n-frags per wave
    constexpr int WNW = BN / 4;     // wave n-width
    constexpr int LB  = BN / 128;   // gl_lds per thread per B half-stage
    constexpr int SBH = BN * 32;    // shorts per B half-array
    constexpr int WS  = 3 * LB + 2; // steady vmcnt

    __shared__ __align__(16) short SA[16384];     // 2 buf x {klo,khi} x 128x32
    __shared__ __align__(16) short SB[4 * SBH];   // 2 buf x {klo,khi} x BNx32
    __shared__ float rsrow[RMS ? 128 : 1];

    const int tid = threadIdx.x;
    const int lane = tid & 63, w = tid >> 6;
    const int wm = w >> 2, wn = w & 3;
    const int lr = lane & 15, lk = lane >> 4;

    // XCD-chunked swizzle: each XCD gets 8 contiguous m-rows x all n-tiles.
    const int NX = gridDim.x;
    {
    }
    int L = blockIdx.y * NX + blockIdx.x;
    int nwg = NX * gridDim.y;                     // % 8 == 0 for both GEMMs
    int Lx = (L & 7) * (nwg >> 3) + (L >> 3);
    const int m0 = (Lx / NX) * 128, n0 = (Lx % NX) * BN;

    // ---- staging source pointers (pre-swizzled global addresses) ----
    const int la = tid >> 2;
    const int rA = (la & ~5) | ((la & 1) << 2) | ((la >> 2) & 1);   // swap02
    const bf16* pA = Ap + (size_t)(m0 + rA) * LDA + (((tid & 3) ^ (rA & 3)) * 8);
    const bf16* pB[LB];
#pragma unroll
    for (int q = 0; q < LB; q++) {
        int lb = (w * LB + q) * 16 + (lane >> 2);
        int rB = (lb & ~5) | ((lb & 1) << 2) | ((lb >> 2) & 1);
        pB[q] = Wp + (size_t)(n0 + rB) * K + (((lane & 3) ^ (rB & 3)) * 8);
    }

    auto stA = [&](int d, int h, int t) {
        gl_lds16(pA + t * 64 + h * 32, (bf16*)&SA[(d * 2 + h) * 4096 + tid * 8]);
    };
    auto stB = [&](int d, int h, int t) {
#pragma unroll
        for (int q = 0; q < LB; q++)
            gl_lds16(pB[q] + t * 64 + h * 32,
                     (bf16*)&SB[(d * 2 + h) * SBH + (w * LB + q) * 512 + lane * 8]);
    };

    // ---- fragment read offsets (shorts) ----
    const int lnsw = (lr & 10) | ((lr & 1) << 2) | ((lr >> 2) & 1); // swap02(lr)
    const int pe = (lk ^ (lr & 3)) * 8;
    const int aBase = (wm * 64 + lnsw) * 32 + pe;   // + i*512 + h*4096 + d*8192
    const int bBase = (wn * WNW + lnsw) * 32 + pe;  // + j*512 + h*SBH + d*2*SBH

    f32x4 acc[4][NJ];
#pragma unroll
    for (int i = 0; i < 4; i++)
#pragma unroll
        for (int j = 0; j < NJ; j++) acc[i][j] = (f32x4){0.f, 0.f, 0.f, 0.f};
    float ssq[4] = {0.f, 0.f, 0.f, 0.f};

#define CLUSTER(I0, I1)                                              \
    do {                                                             \
        __builtin_amdgcn_s_barrier();                                \
        asm volatile("s_waitcnt lgkmcnt(0)" ::: "memory");           \
        __builtin_amdgcn_sched_barrier(0);                           \
        __builtin_amdgcn_s_setprio(1);                               \
        _Pragma("unroll")                                            \
        for (int j = 0; j < NJ; ++j) {                               \
            acc[I0][j] = MF(af[0], bfr[j], acc[I0][j]);              \
            acc[I1][j] = MF(af[1], bfr[j], acc[I1][j]);              \
        }                                                            \
        __builtin_amdgcn_s_setprio(0);                               \
    } while (0)

#define SSQ2(I0, I1)                                                 \
    if constexpr (RMS) {                                             \
        _Pragma("unroll")                                            \
        for (int e = 0; e < 8; ++e) {                                \
            float v0 = bits2f(af[0][e]), v1 = bits2f(af[1][e]);      \
            ssq[I0] += v0 * v0; ssq[I1] += v1 * v1;                  \
        }                                                            \
    }

    // ---- prologue: emulate steady-state issue order ----
    stB(0, 0, 0); stA(0, 0, 0); stB(0, 1, 0); stA(0, 1, 0);
    stB(1, 0, 1); stA(1, 0, 1); stB(1, 1, 1);
    vmw<WS>();
    __builtin_amdgcn_s_barrier();

#pragma unroll
    for (int t = 0; t < NT; ++t) {
        const int d = t & 1;
        const int A0 = d * 8192, A1 = A0 + 4096;
        const int B0 = d * 2 * SBH, B1 = B0 + SBH;
        short8 af[2], bfr[NJ];
        // ---------- P0: B k-lo + A frags 0,1 k-lo ----------
#pragma unroll
        for (int j = 0; j < NJ; ++j) bfr[j] = *(const short8*)&SB[B0 + bBase + j * 512];
        af[0] = *(const short8*)&SA[A0 + aBase];
        af[1] = *(const short8*)&SA[A0 + aBase + 512];
        if (t + 1 < NT) stA(d ^ 1, 1, t + 1);
        CLUSTER(0, 1);
        SSQ2(0, 1);
        __builtin_amdgcn_s_barrier();
        // ---------- P1: A frags 2,3 k-lo ----------
        af[0] = *(const short8*)&SA[A0 + aBase + 1024];
        af[1] = *(const short8*)&SA[A0 + aBase + 1536];
        if (t + 2 < NT) stB(d, 0, t + 2);
        CLUSTER(2, 3);
        SSQ2(2, 3);
        if (t < NT - 2) vmw<WS>();
        else if (t == NT - 2) vmw<2 * LB + 2>();
        else vmw<0>();
        __builtin_amdgcn_s_barrier();
        // ---------- P2: B k-hi + A frags 0,1 k-hi ----------
#pragma unroll
        for (int j = 0; j < NJ; ++j) bfr[j] = *(const short8*)&SB[B1 + bBase + j * 512];
        af[0] = *(const short8*)&SA[A1 + aBase];
        af[1] = *(const short8*)&SA[A1 + aBase + 512];
        if (t + 2 < NT) stA(d, 0, t + 2);
        CLUSTER(0, 1);
        SSQ2(0, 1);
        __builtin_amdgcn_s_barrier();
        // ---------- P3: A frags 2,3 k-hi ----------
        af[0] = *(const short8*)&SA[A1 + aBase + 1024];
        af[1] = *(const short8*)&SA[A1 + aBase + 1536];
        if (t + 2 < NT) stB(d, 1, t + 2);
        CLUSTER(2, 3);
        SSQ2(2, 3);
        if (t < NT - 2) vmw<WS>();
        else if (t == NT - 2) vmw<LB + 1>();
        __builtin_amdgcn_s_barrier();
    }
#undef CLUSTER
#undef SSQ2

    if constexpr (RMS) {
        // ssq reduce over the 4 lk lanes holding the same row (lr fixed);
        // wn-duplicate waves write identical rsrow values (benign).
#pragma unroll
        for (int i = 0; i < 4; i++) {
            float s = ssq[i];
            s += __shfl_down(s, 32);
            s += __shfl_down(s, 16);
            if (lane < 16) rsrow[wm * 64 + i * 16 + lane] = rsqrtf(s * (1.0f / DINNER) + 1e-5f);
        }
        __syncthreads();
#pragma unroll
        for (int i = 0; i < 4; i++) {
            int rl = wm * 64 + i * 16 + lk * 4;
            int row = m0 + rl;
#pragma unroll
            for (int rr = 0; rr < 4; rr++) {
                float s = rsrow[rl + rr];
#pragma unroll
                for (int j = 0; j < NJ; j++) {
                    int col = n0 + wn * WNW + j * 16 + lr;
                    Cp[(size_t)(row + rr) * LDC + col] = acc[i][j][rr] * s;
                }
            }
        }
    } else {
#pragma unroll
        for (int i = 0; i < 4; i++) {
            int row = m0 + wm * 64 + i * 16 + lk * 4;
#pragma unroll
            for (int j = 0; j < NJ; j++) {
                int col = n0 + wn * WNW + j * 16 + lr;
                bf16* cp = (bf16*)Cp + (size_t)row * LDC + col;
#pragma unroll
                for (int rr = 0; rr < 4; rr++) cp[(size_t)rr * LDC] = __float2bfloat16(acc[i][j][rr]);
            }
        }
    }
}

// ---------------- fused: u row -> bf16 + dt projection (dt stored [h][t]) ----------------
__global__ __launch_bounds__(256) void k_prep(const float* __restrict__ u, const float* __restrict__ W_in,
                                              const float* __restrict__ dt_bias,
                                              bf16* __restrict__ u_b, float* __restrict__ dtt) {
    __shared__ __align__(16) float us[8 * DMODEL];
    const int t0 = blockIdx.x * 8;
    const int tid = threadIdx.x;
    const float* ur = u + (size_t)t0 * DMODEL;
    bf16* ub = u_b + (size_t)t0 * DMODEL;
#pragma unroll
    for (int i = 0; i < 8; i++) {
        int idx = (i * 256 + tid) * 4;
        f32x4 v = *(const f32x4*)&ur[idx];
        *(f32x4*)&us[idx] = v;
        short4_ o;
#pragma unroll
        for (int j = 0; j < 4; j++) o[j] = f2bits(v[j]);
        *(short4_*)&ub[idx] = o;
    }
    __syncthreads();
    const int h = tid >> 3, sub = tid & 7;
    const float* wr = W_in + (size_t)(DPROJ - NH + h) * DMODEL;
    float s[8] = {};
    for (int k = sub * 4; k < DMODEL; k += 32) {
        f32x4 w4 = *(const f32x4*)&wr[k];
#pragma unroll
        for (int rr = 0; rr < 8; rr++) {
            const float* up = &us[rr * DMODEL + k];
            s[rr] += up[0] * w4[0] + up[1] * w4[1] + up[2] * w4[2] + up[3] * w4[3];
        }
    }
#pragma unroll
    for (int rr = 0; rr < 8; rr++) {
        s[rr] += __shfl_down(s[rr], 4, 8);
        s[rr] += __shfl_down(s[rr], 2, 8);
        s[rr] += __shfl_down(s[rr], 1, 8);
    }
    if (sub == 0) {
        float bh = dt_bias[h];
#pragma unroll
        for (int rr = 0; rr < 8; rr++) {
            float x = s[rr] + bh;
            dtt[(size_t)h * MTOT + t0 + rr] = (x > 20.f) ? x : log1pf(__expf(x));
        }
    }
}

// ---------------- depthwise causal conv (width 4) + bias + SiLU — 4 channels/thread ----------------
__global__ void k_conv(const bf16* __restrict__ zx, const float* __restrict__ cw,
                       const float* __restrict__ cb, bf16* __restrict__ xbc) {
    int g = (blockIdx.x * 256 + threadIdx.x) * 4;
    if (g >= MTOT * CONVD) return;
    int c0 = g % CONVD;
    int t = g / CONVD;
    int s = t & (SEQ - 1);
    const short* base = (const short*)(zx + (size_t)t * N1 + DINNER + c0);
    f32x4 w0 = *(const f32x4*)&cw[(c0 + 0) * 4];
    f32x4 w1 = *(const f32x4*)&cw[(c0 + 1) * 4];
    f32x4 w2 = *(const f32x4*)&cw[(c0 + 2) * 4];
    f32x4 w3 = *(const f32x4*)&cw[(c0 + 3) * 4];
    f32x4 a = *(const f32x4*)&cb[c0];
#pragma unroll
    for (int k = 0; k < 4; k++) {
        int st = s - 3 + k;
        if (st >= 0) {
            short4_ v = *(const short4_*)(base + (long)(k - 3) * N1);
            a[0] += bits2f(v[0]) * w0[k];
            a[1] += bits2f(v[1]) * w1[k];
            a[2] += bits2f(v[2]) * w2[k];
            a[3] += bits2f(v[3]) * w3[k];
        }
    }
    short4_ o;
#pragma unroll
    for (int j = 0; j < 4; j++) o[j] = f2bits(a[j] * sigmoidf_(a[j]));
    *(short4_*)&xbc[g] = o;
}

// ---------------- fused SSD scan: single barrier/chunk, parity double-buffered tiles ----------------
__global__ __launch_bounds__(256) void k_ssd(const bf16* __restrict__ xbc, const float* __restrict__ dtt,
                                             const float* __restrict__ A_log, const float* __restrict__ Dp,
                                             bf16* __restrict__ zx) {
    __shared__ __align__(16) short Ct[2][64 * YSTR];  // C [l][n]; own-wave rows reused as Y [l][p]
    __shared__ __align__(16) short Bt[2][64 * YSTR];  // B [s][n]
    __shared__ __align__(16) short Bn[2][64 * YSTR];  // B^T [n][l]
    __shared__ __align__(16) short Xt[2][32 * YSTR];  // X^T [p][l]
    __shared__ __align__(16) short Sb[2][32 * YSTR];  // state bf16 [p][n] at chunk start
    __shared__ __align__(16) short Gs[4 * 16 * YSTR]; // per-wave G
    __shared__ __align__(16) float Sf[32 * 68];       // running state fp32 [p][n]
    __shared__ __align__(16) float sdt2[2][64], sAc2[2][64], sf2[2][64];
    __shared__ float set2[2];

    const int ph = blockIdx.x, h = blockIdx.y, b = blockIdx.z;
    const int tid = threadIdx.x;
    const int lane = tid & 63, w = tid >> 6;
    const int lr = lane & 15, lk = lane >> 4;
    const float Ah = -__expf(A_log[h]);
    const float Dh = Dp[h];
    const int xcol = h * HD + ph * 32;

    const int lrow = tid >> 2, c0 = (tid & 3) * 16, px = (tid & 3) * 8;
    const int zl = 16 * w + (lane >> 2), zp = (lane & 3) * 8;

    short8 rC0, rC1, rB0, rB1, rX, rZ;
    float rdt;
    auto load_chunk = [&](int cc) {
        int rows0 = b * SEQ + cc * CKL;
        const short* rp = (const short*)(xbc + (size_t)(rows0 + lrow) * CONVD);
        rC0 = *(const short8*)&rp[DINNER + DSTATE + c0];
        rC1 = *(const short8*)&rp[DINNER + DSTATE + c0 + 8];
        rB0 = *(const short8*)&rp[DINNER + c0];
        rB1 = *(const short8*)&rp[DINNER + c0 + 8];
        rX  = *(const short8*)&rp[xcol + px];
        rZ  = *(const short8*)((const short*)zx + (size_t)(rows0 + zl) * N1 + xcol + zp);
        rdt = dtt[(size_t)h * MTOT + rows0 + lane];
    };
    auto scatter = [&](int buf) {
        *(short8*)&Ct[buf][lrow * YSTR + c0] = rC0;
        *(short8*)&Ct[buf][lrow * YSTR + c0 + 8] = rC1;
        *(short8*)&Bt[buf][lrow * YSTR + c0] = rB0;
        *(short8*)&Bt[buf][lrow * YSTR + c0 + 8] = rB1;
#pragma unroll
        for (int j = 0; j < 8; j++) {
            Bn[buf][(c0 + j) * YSTR + lrow] = rB0[j];
            Bn[buf][(c0 + 8 + j) * YSTR + lrow] = rB1[j];
            Xt[buf][(px + j) * YSTR + lrow] = rX[j];
        }
    };
    auto dtscan = [&](int buf) {
        if (tid < 64) {
            float dv = rdt;
            float v = Ah * dv;
#pragma unroll
            for (int d = 1; d < 64; d <<= 1) { float o = __shfl_up(v, d); if (tid >= d) v += o; }
            float tot = __shfl(v, 63);
            sdt2[buf][tid] = dv; sAc2[buf][tid] = v; sf2[buf][tid] = __expf(tot - v) * dv;
            if (tid == 63) set2[buf] = __expf(tot);
        }
    };

    for (int i = tid; i < 32 * 68; i += 256) Sf[i] = 0.f;
    for (int i = tid; i < 32 * YSTR; i += 256) Sb[0][i] = 0;
    load_chunk(0);
    scatter(0);
    dtscan(0);
    __syncthreads();

    for (int c = 0; c < NCH; c++) {
        const int par = c & 1, nb = par ^ 1;
        const int rows0 = b * SEQ + c * CKL;
        float etot = set2[par];
        short8 zcur = rZ;                 // z of chunk c (loaded last iteration / pre-loop)
        if (c + 1 < NCH) load_chunk(c + 1);

        short8 cf0 = *(const short8*)&Ct[par][(16 * w + lr) * YSTR + lk * 8];
        short8 cf1 = *(const short8*)&Ct[par][(16 * w + lr) * YSTR + 32 + lk * 8];
        // P1: Y_off = C * S0^T
        f32x4 acc[2];
#pragma unroll
        for (int t = 0; t < 2; t++) {
            short8 s0 = *(const short8*)&Sb[par][(16 * t + lr) * YSTR + lk * 8];
            short8 s1 = *(const short8*)&Sb[par][(16 * t + lr) * YSTR + 32 + lk * 8];
            acc[t] = __builtin_amdgcn_mfma_f32_16x16x32_bf16(cf0, s0, (f32x4){0.f, 0.f, 0.f, 0.f}, 0, 0, 0);
            acc[t] = __builtin_amdgcn_mfma_f32_16x16x32_bf16(cf1, s1, acc[t], 0, 0, 0);
        }
        float sAcl[4], el[4];
#pragma unroll
        for (int rr = 0; rr < 4; rr++) { sAcl[rr] = sAc2[par][16 * w + lk * 4 + rr]; el[rr] = __expf(sAcl[rr]); }
#pragma unroll
        for (int t = 0; t < 2; t++)
#pragma unroll
            for (int rr = 0; rr < 4; rr++) acc[t][rr] *= el[rr];
        // P2: G = C * B^T, mask/decay, wave-private LDS round-trip
        short* gw = Gs + w * 16 * YSTR;
#pragma unroll
        for (int t = 0; t < 4; t++) {
            short8 b0 = *(const short8*)&Bt[par][(16 * t + lr) * YSTR + lk * 8];
            short8 b1 = *(const short8*)&Bt[par][(16 * t + lr) * YSTR + 32 + lk * 8];
            f32x4 g = __builtin_amdgcn_mfma_f32_16x16x32_bf16(cf0, b0, (f32x4){0.f, 0.f, 0.f, 0.f}, 0, 0, 0);
            g = __builtin_amdgcn_mfma_f32_16x16x32_bf16(cf1, b1, g, 0, 0, 0);
            int s = 16 * t + lr;
            float sAcs = sAc2[par][s], dts = sdt2[par][s];
#pragma unroll
            for (int rr = 0; rr < 4; rr++) {
                int l = 16 * w + lk * 4 + rr;
                float v = (s <= l) ? g[rr] * __expf(sAcl[rr] - sAcs) * dts : 0.f;
                gw[(lk * 4 + rr) * YSTR + s] = f2bits(v);
            }
        }
        // P3: Y += G * X
        short8 gf0 = *(const short8*)&gw[lr * YSTR + lk * 8];
        short8 gf1 = *(const short8*)&gw[lr * YSTR + 32 + lk * 8];
#pragma unroll
        for (int t = 0; t < 2; t++) {
            short8 x0 = *(const short8*)&Xt[par][(16 * t + lr) * YSTR + lk * 8];
            short8 x1 = *(const short8*)&Xt[par][(16 * t + lr) * YSTR + 32 + lk * 8];
            acc[t] = __builtin_amdgcn_mfma_f32_16x16x32_bf16(gf0, x0, acc[t], 0, 0, 0);
            acc[t] = __builtin_amdgcn_mfma_f32_16x16x32_bf16(gf1, x1, acc[t], 0, 0, 0);
        }
        // P4: Snew = (Xt*sf) * Bn^T ; Sf = Sf*etot + Snew ; Sb[nb] = bf16(Sf)
        {
            int pw = w & 1, nh2 = w >> 1;
            short8 xt0 = *(const short8*)&Xt[par][(16 * pw + lr) * YSTR + lk * 8];
            short8 xt1 = *(const short8*)&Xt[par][(16 * pw + lr) * YSTR + 32 + lk * 8];
            f32x4 sa0 = *(const f32x4*)&sf2[par][lk * 8];
            f32x4 sa1 = *(const f32x4*)&sf2[par][lk * 8 + 4];
            f32x4 sb0 = *(const f32x4*)&sf2[par][32 + lk * 8];
            f32x4 sb1 = *(const f32x4*)&sf2[par][32 + lk * 8 + 4];
            short8 xd0, xd1;
#pragma unroll
            for (int j = 0; j < 4; j++) {
                xd0[j]     = f2bits(bits2f(xt0[j])     * sa0[j]);
                xd0[4 + j] = f2bits(bits2f(xt0[4 + j]) * sa1[j]);
                xd1[j]     = f2bits(bits2f(xt1[j])     * sb0[j]);
                xd1[4 + j] = f2bits(bits2f(xt1[4 + j]) * sb1[j]);
            }
#pragma unroll
            for (int j = 0; j < 2; j++) {
                int nt = 2 * nh2 + j;
                short8 b0 = *(const short8*)&Bn[par][(16 * nt + lr) * YSTR + lk * 8];
                short8 b1 = *(const short8*)&Bn[par][(16 * nt + lr) * YSTR + 32 + lk * 8];
                f32x4 sacc = __builtin_amdgcn_mfma_f32_16x16x32_bf16(xd0, b0, (f32x4){0.f, 0.f, 0.f, 0.f}, 0, 0, 0);
                sacc = __builtin_amdgcn_mfma_f32_16x16x32_bf16(xd1, b1, sacc, 0, 0, 0);
#pragma unroll
                for (int rr = 0; rr < 4; rr++) {
                    int n = 16 * nt + lr;
                    int p = 16 * pw + lk * 4 + rr;
                    float nv = Sf[p * 68 + n] * etot + sacc[rr];
                    Sf[p * 68 + n] = nv;
                    Sb[nb][p * YSTR + n] = f2bits(nv);
                }
            }
        }
        // Y epilogue (+D*x) into Ct[par]'s own wave rows; coalesced z-gate
#pragma unroll
        for (int t = 0; t < 2; t++) {
#pragma unroll
            for (int rr = 0; rr < 4; rr++) {
                int p = 16 * t + lr;
                int l = 16 * w + lk * 4 + rr;
                float y = acc[t][rr] + Dh * bits2f(Xt[par][p * YSTR + l]);
                Ct[par][l * YSTR + p] = f2bits(y);
            }
        }
        {
            short8 y8 = *(const short8*)&Ct[par][zl * YSTR + zp];
            short* zpp = (short*)zx + (size_t)(rows0 + zl) * N1 + xcol + zp;
            short8 o;
#pragma unroll
            for (int j = 0; j < 8; j++) {
                float z = bits2f(zcur[j]);
                o[j] = f2bits(bits2f(y8[j]) * (z * sigmoidf_(z)));
            }
            *(short8*)zpp = o;
        }
        // stage chunk c+1 (off critical path: independent of this chunk's compute)
        if (c + 1 < NCH) {
            scatter(nb);
            dtscan(nb);
        }
        __syncthreads();
    }
}

extern "C" void kernel_launch(void* const* d_in, const int* in_sizes, int n_in,
                              void* d_out, int out_size, void* d_ws, size_t ws_size,
                              hipStream_t stream) {
    const float* u       = (const float*)d_in[0];
    const float* W_in    = (const float*)d_in[1];
    const float* conv_w  = (const float*)d_in[2];
    const float* conv_b  = (const float*)d_in[3];
    const float* dt_bias = (const float*)d_in[4];
    const float* A_log   = (const float*)d_in[5];
    const float* Dp      = (const float*)d_in[6];
    const float* norm_w  = (const float*)d_in[7];
    const float* W_out   = (const float*)d_in[8];
    float* out = (float*)d_out;

    // Workspace layout (~108 MiB total):
    char* ws = (char*)d_ws;
    bf16* zx     = (bf16*)ws;  ws += (size_t)MTOT * N1 * 2;       // 69.2 MB
    bf16* xbc    = (bf16*)ws;  ws += (size_t)MTOT * CONVD * 2;    // 34 MB
    bf16* wout_b = (bf16*)ws;  ws += (size_t)DMODEL * DINNER * 2; // 4 MB
    float* dtt   = (float*)ws; ws += (size_t)NH * MTOT * 4;       // 1 MB, [h][t]

    // d_out (32 MiB) doubles as scratch for GEMM1 inputs only.
    bf16* u_b   = (bf16*)d_out;                                      // 16 MB
    bf16* win_b = (bf16*)((char*)d_out + (size_t)MTOT * DMODEL * 2); // 8.25 MB

    k_prep<<<MTOT / 8, 256, 0, stream>>>(u, W_in, dt_bias, u_b, dtt);
    k_cvt2<<<((N1 * DMODEL + DMODEL * DINNER) / 4 + 255) / 256, 256, 0, stream>>>(
        W_in, W_out, norm_w, win_b, wout_b);

    // GEMM1: zx[8192][4224] = u_b[8192][1024] * win_b[4224][1024]^T
    k_mm8<384, 16, DMODEL, N1, false, bf16>
        <<<dim3(N1 / 384, MTOT / 128), 512, 0, stream>>>(u_b, win_b, zx);

    k_conv<<<(MTOT * CONVD / 4 + 255) / 256, 256, 0, stream>>>(zx, conv_w, conv_b, xbc);

    k_ssd<<<dim3(2, NH, BSZ), 256, 0, stream>>>(xbc, dtt, A_log, Dp, zx);

    // GEMM2 (+fused RMSNorm): out[8192][1024] = gated_y(zx)[8192][2048] * wout_b[1024][2048]^T
    k_mm8<256, 32, N1, DMODEL, true, float>
        <<<dim3(DMODEL / 256, MTOT / 128), 512, 0, stream>>>(zx, wout_b, out);
}

// Round 2
// 393.759 us; speedup vs baseline: 1.4130x; 1.4130x over previous
//
#include <hip/hip_runtime.h>
#include <hip/hip_bf16.h>

#define BSZ 4
#define SEQ 2048
#define DMODEL 1024
#define DINNER 2048
#define DSTATE 64
#define NH 32
#define HD 64
#define CKL 64            // chunk length
#define NCH 32            // chunks per sequence
#define CONVD 2176
#define DPROJ 4256
#define N1 4224           // GEMM1 N = DINNER + CONVD = 33*128 (dt cols handled separately)
#define MTOT 8192         // BSZ*SEQ
#define YSTR 72           // LDS row stride (bf16): 144 B, keeps 16B alignment

typedef __hip_bfloat16 bf16;
typedef __attribute__((ext_vector_type(8))) short short8;   // 8 bf16 (4 VGPRs)
typedef __attribute__((ext_vector_type(4))) short short4_;  // 8 bytes
typedef __attribute__((ext_vector_type(4))) float f32x4;

__device__ __forceinline__ float sigmoidf_(float x) { return 1.0f / (1.0f + __expf(-x)); }
__device__ __forceinline__ float bits2f(short s) { return __uint_as_float(((unsigned)(unsigned short)s) << 16); }
__device__ __forceinline__ short f2bits(float f) {
    bf16 h = __float2bfloat16(f);
    return *reinterpret_cast<short*>(&h);
}

__device__ __forceinline__ void gl_lds16(const bf16* g, bf16* l) {
    __builtin_amdgcn_global_load_lds((const __attribute__((address_space(1))) void*)g,
                                     (__attribute__((address_space(3))) void*)l, 16, 0, 0);
}

// XCD-chunked locality swizzle (T1, bijective: nwg % 8 == 0 for both GEMMs).
// Hardware assigns consecutive raw block ids round-robin to the 8 XCDs; we
// give each XCD a CONTIGUOUS chunk of the locality-ordered index so that a
// group of 8 m-rows x all n-tiles stays on one XCD (A-slab L2-resident,
// B panels stream through that XCD's L2 once).
__device__ __forceinline__ void swzx(int& bx, int& by) {
    int nx = gridDim.x;
    int nwg = nx * gridDim.y;
    int Lr = blockIdx.y * nx + blockIdx.x;
    int L = (Lr & 7) * (nwg >> 3) + (Lr >> 3);   // contiguous chunk per XCD
    int GSZ = nx * 8;
    int g = L / GSZ, r = L - g * GSZ;
    bx = r % nx;
    by = g * 8 + r / nx;
}

// ---------------- both weight converts in one launch ----------------
__global__ void k_cvt2(const float* __restrict__ W_in, const float* __restrict__ W_out,
                       const float* __restrict__ nw, bf16* __restrict__ win_b,
                       bf16* __restrict__ wout_b) {
    int g = (blockIdx.x * 256 + threadIdx.x) * 4;
    if (g < N1 * DMODEL) {
        f32x4 f = *(const f32x4*)&W_in[g];
        short4_ o;
#pragma unroll
        for (int j = 0; j < 4; j++) o[j] = f2bits(f[j]);
        *(short4_*)&win_b[g] = o;
    } else if (g < N1 * DMODEL + DMODEL * DINNER) {
        int g2 = g - N1 * DMODEL;
        f32x4 f = *(const f32x4*)&W_out[g2];
        f32x4 w = *(const f32x4*)&nw[g2 & (DINNER - 1)];
        short4_ o;
#pragma unroll
        for (int j = 0; j < 4; j++) o[j] = f2bits(f[j] * w[j]);
        *(short4_*)&wout_b[g2] = o;
    }
}

// ---------------- bf16 MFMA GEMM1: C[M][N](bf16) = A[M][K] * W[N][K]^T ----------
// 128x128 tile, BK=64, XOR-swizzled LDS (conflict-free), XCD-chunked swizzle.
__global__ __launch_bounds__(256) void k_gemm_bt(const bf16* __restrict__ A, const bf16* __restrict__ W,
                                                 bf16* __restrict__ C, int N, int K, int lda) {
    __shared__ __align__(16) bf16 lA[128 * 64];
    __shared__ __align__(16) bf16 lB[128 * 64];
    const int tid = threadIdx.x;
    const int lane = tid & 63, w = tid >> 6;
    const int wm = w >> 1, wn = w & 1;
    const int lr = lane & 15, lk = lane >> 4;
    int bx, by;
    swzx(bx, by);
    const int m0 = by * 128, n0 = bx * 128;

    f32x4 acc[4][4];
#pragma unroll
    for (int i = 0; i < 4; i++)
#pragma unroll
        for (int j = 0; j < 4; j++) acc[i][j] = (f32x4){0.f, 0.f, 0.f, 0.f};

    const int r = tid >> 3;
    const int cs = ((tid & 7) ^ (r & 7)) * 8;
    const bf16* ga = A + (size_t)(m0 + r) * lda + cs;
    const bf16* gb = W + (size_t)(n0 + r) * K + cs;
    bf16* la0 = lA + tid * 8;
    bf16* lb0 = lB + tid * 8;
    const int sx = (lr & 7);

    for (int kt = 0; kt < K; kt += 64) {
#pragma unroll
        for (int i = 0; i < 4; i++) {
            gl_lds16(ga + kt + (size_t)(32 * i) * lda, la0 + 2048 * i);
            gl_lds16(gb + kt + (size_t)(32 * i) * K, lb0 + 2048 * i);
        }
        __syncthreads();
#pragma unroll
        for (int hh = 0; hh < 2; hh++) {
            const int cb = ((lk + 4 * hh) ^ sx) * 8;
            short8 af[4], bfr[4];
#pragma unroll
            for (int im = 0; im < 4; im++)
                af[im] = *(const short8*)&lA[(wm * 64 + im * 16 + lr) * 64 + cb];
#pragma unroll
            for (int jn = 0; jn < 4; jn++)
                bfr[jn] = *(const short8*)&lB[(wn * 64 + jn * 16 + lr) * 64 + cb];
#pragma unroll
            for (int im = 0; im < 4; im++)
#pragma unroll
                for (int jn = 0; jn < 4; jn++)
                    acc[im][jn] = __builtin_amdgcn_mfma_f32_16x16x32_bf16(af[im], bfr[jn], acc[im][jn], 0, 0, 0);
        }
        __syncthreads();
    }
#pragma unroll
    for (int im = 0; im < 4; im++) {
        int row = m0 + wm * 64 + im * 16 + lk * 4;
#pragma unroll
        for (int jn = 0; jn < 4; jn++) {
            int col = n0 + wn * 64 + jn * 16 + lr;
            bf16* cp = C + (size_t)row * N + col;
#pragma unroll
            for (int rr = 0; rr < 4; rr++) cp[(size_t)rr * N] = __float2bfloat16(acc[im][jn][rr]);
        }
    }
}

// ---------------- GEMM2 with fused RMSNorm: 128x128 tile, 512 blocks (2/CU) ----------------
// A = gated y in zx (lda=N1, K=2048), W = wout_b (norm_w folded). ssq from A-fragments;
// wn-duplicate waves compute/write identical rsrow values (benign).
__global__ __launch_bounds__(256) void k_gemm2(const bf16* __restrict__ A, const bf16* __restrict__ W,
                                               float* __restrict__ C) {
    __shared__ __align__(16) bf16 lA[128 * 64];
    __shared__ __align__(16) bf16 lB[128 * 64];
    __shared__ float rsrow[128];
    const int tid = threadIdx.x;
    const int lane = tid & 63, w = tid >> 6;
    const int wm = w >> 1, wn = w & 1;
    const int lr = lane & 15, lk = lane >> 4;
    int bx, by;
    swzx(bx, by);
    const int m0 = by * 128, n0 = bx * 128;
    const int K = DINNER, N = DMODEL;

    f32x4 acc[4][4];
#pragma unroll
    for (int i = 0; i < 4; i++)
#pragma unroll
        for (int j = 0; j < 4; j++) acc[i][j] = (f32x4){0.f, 0.f, 0.f, 0.f};
    float ssq[4] = {0.f, 0.f, 0.f, 0.f};

    const int r = tid >> 3;
    const int cs = ((tid & 7) ^ (r & 7)) * 8;
    const bf16* ga = A + (size_t)(m0 + r) * N1 + cs;
    const bf16* gb = W + (size_t)(n0 + r) * K + cs;
    bf16* la0 = lA + tid * 8;
    bf16* lb0 = lB + tid * 8;
    const int sx = (lr & 7);

    for (int kt = 0; kt < K; kt += 64) {
#pragma unroll
        for (int i = 0; i < 4; i++) {
            gl_lds16(ga + kt + (size_t)(32 * i) * N1, la0 + 2048 * i);
            gl_lds16(gb + kt + (size_t)(32 * i) * K, lb0 + 2048 * i);
        }
        __syncthreads();
#pragma unroll
        for (int hh = 0; hh < 2; hh++) {
            const int cb = ((lk + 4 * hh) ^ sx) * 8;
            short8 af[4], bfr[4];
#pragma unroll
            for (int im = 0; im < 4; im++) {
                af[im] = *(const short8*)&lA[(wm * 64 + im * 16 + lr) * 64 + cb];
#pragma unroll
                for (int j = 0; j < 8; j++) { float v = bits2f(af[im][j]); ssq[im] += v * v; }
            }
#pragma unroll
            for (int jn = 0; jn < 4; jn++)
                bfr[jn] = *(const short8*)&lB[(wn * 64 + jn * 16 + lr) * 64 + cb];
#pragma unroll
            for (int im = 0; im < 4; im++)
#pragma unroll
                for (int jn = 0; jn < 4; jn++)
                    acc[im][jn] = __builtin_amdgcn_mfma_f32_16x16x32_bf16(af[im], bfr[jn], acc[im][jn], 0, 0, 0);
        }
        __syncthreads();
    }
    // ssq reduce over the 4 lk lanes holding the same row (lr fixed)
#pragma unroll
    for (int im = 0; im < 4; im++) {
        float s = ssq[im];
        s += __shfl_down(s, 32);
        s += __shfl_down(s, 16);
        if (lane < 16) rsrow[wm * 64 + im * 16 + lane] = rsqrtf(s * (1.0f / DINNER) + 1e-5f);
    }
    __syncthreads();
#pragma unroll
    for (int im = 0; im < 4; im++) {
        int rloc = wm * 64 + im * 16 + lk * 4;
        int row = m0 + rloc;
#pragma unroll
        for (int rr = 0; rr < 4; rr++) {
            float s = rsrow[rloc + rr];
#pragma unroll
            for (int jn = 0; jn < 4; jn++) {
                int col = n0 + wn * 64 + jn * 16 + lr;
                C[(size_t)(row + rr) * N + col] = acc[im][jn][rr] * s;
            }
        }
    }
}

// ---------------- fused: u row -> bf16 + dt projection (dt stored [h][t]) ----------------
__global__ __launch_bounds__(256) void k_prep(const float* __restrict__ u, const float* __restrict__ W_in,
                                              const float* __restrict__ dt_bias,
                                              bf16* __restrict__ u_b, float* __restrict__ dtt) {
    __shared__ __align__(16) float us[8 * DMODEL];
    const int t0 = blockIdx.x * 8;
    const int tid = threadIdx.x;
    const float* ur = u + (size_t)t0 * DMODEL;
    bf16* ub = u_b + (size_t)t0 * DMODEL;
#pragma unroll
    for (int i = 0; i < 8; i++) {
        int idx = (i * 256 + tid) * 4;
        f32x4 v = *(const f32x4*)&ur[idx];
        *(f32x4*)&us[idx] = v;
        short4_ o;
#pragma unroll
        for (int j = 0; j < 4; j++) o[j] = f2bits(v[j]);
        *(short4_*)&ub[idx] = o;
    }
    __syncthreads();
    const int h = tid >> 3, sub = tid & 7;
    const float* wr = W_in + (size_t)(DPROJ - NH + h) * DMODEL;
    float s[8] = {};
    for (int k = sub * 4; k < DMODEL; k += 32) {
        f32x4 w4 = *(const f32x4*)&wr[k];
#pragma unroll
        for (int rr = 0; rr < 8; rr++) {
            const float* up = &us[rr * DMODEL + k];
            s[rr] += up[0] * w4[0] + up[1] * w4[1] + up[2] * w4[2] + up[3] * w4[3];
        }
    }
#pragma unroll
    for (int rr = 0; rr < 8; rr++) {
        s[rr] += __shfl_down(s[rr], 4, 8);
        s[rr] += __shfl_down(s[rr], 2, 8);
        s[rr] += __shfl_down(s[rr], 1, 8);
    }
    if (sub == 0) {
        float bh = dt_bias[h];
#pragma unroll
        for (int rr = 0; rr < 8; rr++) {
            float x = s[rr] + bh;
            dtt[(size_t)h * MTOT + t0 + rr] = (x > 20.f) ? x : log1pf(__expf(x));
        }
    }
}

// ---------------- depthwise causal conv (width 4) + bias + SiLU — 4 channels/thread ----------------
__global__ void k_conv(const bf16* __restrict__ zx, const float* __restrict__ cw,
                       const float* __restrict__ cb, bf16* __restrict__ xbc) {
    int g = (blockIdx.x * 256 + threadIdx.x) * 4;
    if (g >= MTOT * CONVD) return;
    int c0 = g % CONVD;
    int t = g / CONVD;
    int s = t & (SEQ - 1);
    const short* base = (const short*)(zx + (size_t)t * N1 + DINNER + c0);
    f32x4 w0 = *(const f32x4*)&cw[(c0 + 0) * 4];
    f32x4 w1 = *(const f32x4*)&cw[(c0 + 1) * 4];
    f32x4 w2 = *(const f32x4*)&cw[(c0 + 2) * 4];
    f32x4 w3 = *(const f32x4*)&cw[(c0 + 3) * 4];
    f32x4 a = *(const f32x4*)&cb[c0];
#pragma unroll
    for (int k = 0; k < 4; k++) {
        int st = s - 3 + k;
        if (st >= 0) {
            short4_ v = *(const short4_*)(base + (long)(k - 3) * N1);
            a[0] += bits2f(v[0]) * w0[k];
            a[1] += bits2f(v[1]) * w1[k];
            a[2] += bits2f(v[2]) * w2[k];
            a[3] += bits2f(v[3]) * w3[k];
        }
    }
    short4_ o;
#pragma unroll
    for (int j = 0; j < 4; j++) o[j] = f2bits(a[j] * sigmoidf_(a[j]));
    *(short4_*)&xbc[g] = o;
}

// ---------------- fused SSD scan: single barrier/chunk, parity double-buffered tiles ----------------
__global__ __launch_bounds__(256) void k_ssd(const bf16* __restrict__ xbc, const float* __restrict__ dtt,
                                             const float* __restrict__ A_log, const float* __restrict__ Dp,
                                             bf16* __restrict__ zx) {
    __shared__ __align__(16) short Ct[2][64 * YSTR];  // C [l][n]; own-wave rows reused as Y [l][p]
    __shared__ __align__(16) short Bt[2][64 * YSTR];  // B [s][n]
    __shared__ __align__(16) short Bn[2][64 * YSTR];  // B^T [n][l]
    __shared__ __align__(16) short Xt[2][32 * YSTR];  // X^T [p][l]
    __shared__ __align__(16) short Sb[2][32 * YSTR];  // state bf16 [p][n] at chunk start
    __shared__ __align__(16) short Gs[4 * 16 * YSTR]; // per-wave G
    __shared__ __align__(16) float Sf[32 * 68];       // running state fp32 [p][n]
    __shared__ __align__(16) float sdt2[2][64], sAc2[2][64], sf2[2][64];
    __shared__ float set2[2];

    const int ph = blockIdx.x, h = blockIdx.y, b = blockIdx.z;
    const int tid = threadIdx.x;
    const int lane = tid & 63, w = tid >> 6;
    const int lr = lane & 15, lk = lane >> 4;
    const float Ah = -__expf(A_log[h]);
    const float Dh = Dp[h];
    const int xcol = h * HD + ph * 32;

    const int lrow = tid >> 2, c0 = (tid & 3) * 16, px = (tid & 3) * 8;
    const int zl = 16 * w + (lane >> 2), zp = (lane & 3) * 8;

    short8 rC0, rC1, rB0, rB1, rX, rZ;
    float rdt;
    auto load_chunk = [&](int cc) {
        int rows0 = b * SEQ + cc * CKL;
        const short* rp = (const short*)(xbc + (size_t)(rows0 + lrow) * CONVD);
        rC0 = *(const short8*)&rp[DINNER + DSTATE + c0];
        rC1 = *(const short8*)&rp[DINNER + DSTATE + c0 + 8];
        rB0 = *(const short8*)&rp[DINNER + c0];
        rB1 = *(const short8*)&rp[DINNER + c0 + 8];
        rX  = *(const short8*)&rp[xcol + px];
        rZ  = *(const short8*)((const short*)zx + (size_t)(rows0 + zl) * N1 + xcol + zp);
        rdt = dtt[(size_t)h * MTOT + rows0 + lane];
    };
    auto scatter = [&](int buf) {
        *(short8*)&Ct[buf][lrow * YSTR + c0] = rC0;
        *(short8*)&Ct[buf][lrow * YSTR + c0 + 8] = rC1;
        *(short8*)&Bt[buf][lrow * YSTR + c0] = rB0;
        *(short8*)&Bt[buf][lrow * YSTR + c0 + 8] = rB1;
#pragma unroll
        for (int j = 0; j < 8; j++) {
            Bn[buf][(c0 + j) * YSTR + lrow] = rB0[j];
            Bn[buf][(c0 + 8 + j) * YSTR + lrow] = rB1[j];
            Xt[buf][(px + j) * YSTR + lrow] = rX[j];
        }
    };
    auto dtscan = [&](int buf) {
        if (tid < 64) {
            float dv = rdt;
            float v = Ah * dv;
#pragma unroll
            for (int d = 1; d < 64; d <<= 1) { float o = __shfl_up(v, d); if (tid >= d) v += o; }
            float tot = __shfl(v, 63);
            sdt2[buf][tid] = dv; sAc2[buf][tid] = v; sf2[buf][tid] = __expf(tot - v) * dv;
            if (tid == 63) set2[buf] = __expf(tot);
        }
    };

    for (int i = tid; i < 32 * 68; i += 256) Sf[i] = 0.f;
    for (int i = tid; i < 32 * YSTR; i += 256) Sb[0][i] = 0;
    load_chunk(0);
    scatter(0);
    dtscan(0);
    __syncthreads();

    for (int c = 0; c < NCH; c++) {
        const int par = c & 1, nb = par ^ 1;
        const int rows0 = b * SEQ + c * CKL;
        float etot = set2[par];
        short8 zcur = rZ;                 // z of chunk c (loaded last iteration / pre-loop)
        if (c + 1 < NCH) load_chunk(c + 1);

        short8 cf0 = *(const short8*)&Ct[par][(16 * w + lr) * YSTR + lk * 8];
        short8 cf1 = *(const short8*)&Ct[par][(16 * w + lr) * YSTR + 32 + lk * 8];
        // P1: Y_off = C * S0^T
        f32x4 acc[2];
#pragma unroll
        for (int t = 0; t < 2; t++) {
            short8 s0 = *(const short8*)&Sb[par][(16 * t + lr) * YSTR + lk * 8];
            short8 s1 = *(const short8*)&Sb[par][(16 * t + lr) * YSTR + 32 + lk * 8];
            acc[t] = __builtin_amdgcn_mfma_f32_16x16x32_bf16(cf0, s0, (f32x4){0.f, 0.f, 0.f, 0.f}, 0, 0, 0);
            acc[t] = __builtin_amdgcn_mfma_f32_16x16x32_bf16(cf1, s1, acc[t], 0, 0, 0);
        }
        float sAcl[4], el[4];
#pragma unroll
        for (int rr = 0; rr < 4; rr++) { sAcl[rr] = sAc2[par][16 * w + lk * 4 + rr]; el[rr] = __expf(sAcl[rr]); }
#pragma unroll
        for (int t = 0; t < 2; t++)
#pragma unroll
            for (int rr = 0; rr < 4; rr++) acc[t][rr] *= el[rr];
        // P2: G = C * B^T, mask/decay, wave-private LDS round-trip
        short* gw = Gs + w * 16 * YSTR;
#pragma unroll
        for (int t = 0; t < 4; t++) {
            short8 b0 = *(const short8*)&Bt[par][(16 * t + lr) * YSTR + lk * 8];
            short8 b1 = *(const short8*)&Bt[par][(16 * t + lr) * YSTR + 32 + lk * 8];
            f32x4 g = __builtin_amdgcn_mfma_f32_16x16x32_bf16(cf0, b0, (f32x4){0.f, 0.f, 0.f, 0.f}, 0, 0, 0);
            g = __builtin_amdgcn_mfma_f32_16x16x32_bf16(cf1, b1, g, 0, 0, 0);
            int s = 16 * t + lr;
            float sAcs = sAc2[par][s], dts = sdt2[par][s];
#pragma unroll
            for (int rr = 0; rr < 4; rr++) {
                int l = 16 * w + lk * 4 + rr;
                float v = (s <= l) ? g[rr] * __expf(sAcl[rr] - sAcs) * dts : 0.f;
                gw[(lk * 4 + rr) * YSTR + s] = f2bits(v);
            }
        }
        // P3: Y += G * X
        short8 gf0 = *(const short8*)&gw[lr * YSTR + lk * 8];
        short8 gf1 = *(const short8*)&gw[lr * YSTR + 32 + lk * 8];
#pragma unroll
        for (int t = 0; t < 2; t++) {
            short8 x0 = *(const short8*)&Xt[par][(16 * t + lr) * YSTR + lk * 8];
            short8 x1 = *(const short8*)&Xt[par][(16 * t + lr) * YSTR + 32 + lk * 8];
            acc[t] = __builtin_amdgcn_mfma_f32_16x16x32_bf16(gf0, x0, acc[t], 0, 0, 0);
            acc[t] = __builtin_amdgcn_mfma_f32_16x16x32_bf16(gf1, x1, acc[t], 0, 0, 0);
        }
        // P4: Snew = (Xt*sf) * Bn^T ; Sf = Sf*etot + Snew ; Sb[nb] = bf16(Sf)
        {
            int pw = w & 1, nh2 = w >> 1;
            short8 xt0 = *(const short8*)&Xt[par][(16 * pw + lr) * YSTR + lk * 8];
            short8 xt1 = *(const short8*)&Xt[par][(16 * pw + lr) * YSTR + 32 + lk * 8];
            f32x4 sa0 = *(const f32x4*)&sf2[par][lk * 8];
            f32x4 sa1 = *(const f32x4*)&sf2[par][lk * 8 + 4];
            f32x4 sb0 = *(const f32x4*)&sf2[par][32 + lk * 8];
            f32x4 sb1 = *(const f32x4*)&sf2[par][32 + lk * 8 + 4];
            short8 xd0, xd1;
#pragma unroll
            for (int j = 0; j < 4; j++) {
                xd0[j]     = f2bits(bits2f(xt0[j])     * sa0[j]);
                xd0[4 + j] = f2bits(bits2f(xt0[4 + j]) * sa1[j]);
                xd1[j]     = f2bits(bits2f(xt1[j])     * sb0[j]);
                xd1[4 + j] = f2bits(bits2f(xt1[4 + j]) * sb1[j]);
            }
#pragma unroll
            for (int j = 0; j < 2; j++) {
                int nt = 2 * nh2 + j;
                short8 b0 = *(const short8*)&Bn[par][(16 * nt + lr) * YSTR + lk * 8];
                short8 b1 = *(const short8*)&Bn[par][(16 * nt + lr) * YSTR + 32 + lk * 8];
                f32x4 sacc = __builtin_amdgcn_mfma_f32_16x16x32_bf16(xd0, b0, (f32x4){0.f, 0.f, 0.f, 0.f}, 0, 0, 0);
                sacc = __builtin_amdgcn_mfma_f32_16x16x32_bf16(xd1, b1, sacc, 0, 0, 0);
#pragma unroll
                for (int rr = 0; rr < 4; rr++) {
                    int n = 16 * nt + lr;
                    int p = 16 * pw + lk * 4 + rr;
                    float nv = Sf[p * 68 + n] * etot + sacc[rr];
                    Sf[p * 68 + n] = nv;
                    Sb[nb][p * YSTR + n] = f2bits(nv);
                }
            }
        }
        // Y epilogue (+D*x) into Ct[par]'s own wave rows; coalesced z-gate
#pragma unroll
        for (int t = 0; t < 2; t++) {
#pragma unroll
            for (int rr = 0; rr < 4; rr++) {
                int p = 16 * t + lr;
                int l = 16 * w + lk * 4 + rr;
                float y = acc[t][rr] + Dh * bits2f(Xt[par][p * YSTR + l]);
                Ct[par][l * YSTR + p] = f2bits(y);
            }
        }
        {
            short8 y8 = *(const short8*)&Ct[par][zl * YSTR + zp];
            short* zpp = (short*)zx + (size_t)(rows0 + zl) * N1 + xcol + zp;
            short8 o;
#pragma unroll
            for (int j = 0; j < 8; j++) {
                float z = bits2f(zcur[j]);
                o[j] = f2bits(bits2f(y8[j]) * (z * sigmoidf_(z)));
            }
            *(short8*)zpp = o;
        }
        // stage chunk c+1 (off critical path: independent of this chunk's compute)
        if (c + 1 < NCH) {
            scatter(nb);
            dtscan(nb);
        }
        __syncthreads();
    }
}

extern "C" void kernel_launch(void* const* d_in, const int* in_sizes, int n_in,
                              void* d_out, int out_size, void* d_ws, size_t ws_size,
                              hipStream_t stream) {
    const float* u       = (const float*)d_in[0];
    const float* W_in    = (const float*)d_in[1];
    const float* conv_w  = (const float*)d_in[2];
    const float* conv_b  = (const float*)d_in[3];
    const float* dt_bias = (const float*)d_in[4];
    const float* A_log   = (const float*)d_in[5];
    const float* Dp      = (const float*)d_in[6];
    const float* norm_w  = (const float*)d_in[7];
    const float* W_out   = (const float*)d_in[8];
    float* out = (float*)d_out;

    // Workspace layout (~108 MiB total):
    char* ws = (char*)d_ws;
    bf16* zx     = (bf16*)ws;  ws += (size_t)MTOT * N1 * 2;       // 69.2 MB
    bf16* xbc    = (bf16*)ws;  ws += (size_t)MTOT * CONVD * 2;    // 34 MB
    bf16* wout_b = (bf16*)ws;  ws += (size_t)DMODEL * DINNER * 2; // 4 MB
    float* dtt   = (float*)ws; ws += (size_t)NH * MTOT * 4;       // 1 MB, [h][t]

    // d_out (32 MiB) doubles as scratch for GEMM1 inputs only.
    bf16* u_b   = (bf16*)d_out;                                      // 16 MB
    bf16* win_b = (bf16*)((char*)d_out + (size_t)MTOT * DMODEL * 2); // 8.25 MB

    k_prep<<<MTOT / 8, 256, 0, stream>>>(u, W_in, dt_bias, u_b, dtt);
    k_cvt2<<<((N1 * DMODEL + DMODEL * DINNER) / 4 + 255) / 256, 256, 0, stream>>>(
        W_in, W_out, norm_w, win_b, wout_b);

    k_gemm_bt<<<dim3(N1 / 128, MTOT / 128), 256, 0, stream>>>(u_b, win_b, zx, N1, DMODEL, DMODEL);

    k_conv<<<(MTOT * CONVD / 4 + 255) / 256, 256, 0, stream>>>(zx, conv_w, conv_b, xbc);

    k_ssd<<<dim3(2, NH, BSZ), 256, 0, stream>>>(xbc, dtt, A_log, Dp, zx);

    k_gemm2<<<dim3(DMODEL / 128, MTOT / 128), 256, 0, stream>>>(zx, wout_b, out);
}

// Round 3
// 390.777 us; speedup vs baseline: 1.4238x; 1.0076x over previous
//
#include <hip/hip_runtime.h>
#include <hip/hip_bf16.h>

#define BSZ 4
#define SEQ 2048
#define DMODEL 1024
#define DINNER 2048
#define DSTATE 64
#define NH 32
#define HD 64
#define CKL 64            // chunk length
#define NCH 32            // chunks per sequence
#define CONVD 2176
#define DPROJ 4256
#define N1 4224           // GEMM1 N = DINNER + CONVD = 22*192
#define MTOT 8192         // BSZ*SEQ
#define YSTR 72           // LDS row stride (bf16): 144 B, keeps 16B alignment

typedef __hip_bfloat16 bf16;
typedef __attribute__((ext_vector_type(8))) short short8;   // 8 bf16 (4 VGPRs)
typedef __attribute__((ext_vector_type(4))) short short4_;  // 8 bytes
typedef __attribute__((ext_vector_type(4))) float f32x4;

__device__ __forceinline__ float sigmoidf_(float x) { return 1.0f / (1.0f + __expf(-x)); }
__device__ __forceinline__ float bits2f(short s) { return __uint_as_float(((unsigned)(unsigned short)s) << 16); }
__device__ __forceinline__ short f2bits(float f) {
    bf16 h = __float2bfloat16(f);
    return *reinterpret_cast<short*>(&h);
}

__device__ __forceinline__ void gl_lds16(const bf16* g, bf16* l) {
    __builtin_amdgcn_global_load_lds((const __attribute__((address_space(1))) void*)g,
                                     (__attribute__((address_space(3))) void*)l, 16, 0, 0);
}

__device__ __forceinline__ f32x4 MF(short8 a, short8 b, f32x4 c) {
    return __builtin_amdgcn_mfma_f32_16x16x32_bf16(a, b, c, 0, 0, 0);
}

// counted s_waitcnt vmcnt(N); "memory" clobber = compiler fence (no load may
// cross it), so a vmw before s_barrier gives a block-wide landing guarantee.
template<int N> __device__ __forceinline__ void vmw() {
    if constexpr (N == 0)      asm volatile("s_waitcnt vmcnt(0)" ::: "memory");
    else if constexpr (N == 3) asm volatile("s_waitcnt vmcnt(3)" ::: "memory");
    else if constexpr (N == 6) asm volatile("s_waitcnt vmcnt(6)" ::: "memory");
    else                       asm volatile("s_waitcnt vmcnt(15)" ::: "memory");
}

// XCD-chunked locality swizzle (bijective: nwg % 8 == 0 for all grids here).
__device__ __forceinline__ void swzx(int& bx, int& by) {
    int nx = gridDim.x;
    int nwg = nx * gridDim.y;
    int Lr = blockIdx.y * nx + blockIdx.x;
    int L = (Lr & 7) * (nwg >> 3) + (Lr >> 3);   // contiguous chunk per XCD
    int GSZ = nx * 8;
    int g = L / GSZ, r = L - g * GSZ;
    bx = r % nx;
    by = g * 8 + r / nx;
}

// ---------------- both weight converts in one launch ----------------
__global__ void k_cvt2(const float* __restrict__ W_in, const float* __restrict__ W_out,
                       const float* __restrict__ nw, bf16* __restrict__ win_b,
                       bf16* __restrict__ wout_b) {
    int g = (blockIdx.x * 256 + threadIdx.x) * 4;
    if (g < N1 * DMODEL) {
        f32x4 f = *(const f32x4*)&W_in[g];
        short4_ o;
#pragma unroll
        for (int j = 0; j < 4; j++) o[j] = f2bits(f[j]);
        *(short4_*)&win_b[g] = o;
    } else if (g < N1 * DMODEL + DMODEL * DINNER) {
        int g2 = g - N1 * DMODEL;
        f32x4 f = *(const f32x4*)&W_out[g2];
        f32x4 w = *(const f32x4*)&nw[g2 & (DINNER - 1)];
        short4_ o;
#pragma unroll
        for (int j = 0; j < 4; j++) o[j] = f2bits(f[j] * w[j]);
        *(short4_*)&wout_b[g2] = o;
    }
}

// Shared phase scaffolding for the counted-vmcnt GEMMs.
// Phase = {ds_reads; stages} -> barrier -> lgkmcnt(0) -> MFMA cluster -> [vmw] -> barrier.
// A wave passing a phase's 2nd barrier has completed its ds_reads (lgkm(0) was
// before MFMA), so stages issued in any later phase may safely overwrite that
// region. vmw<N> BEFORE a barrier makes stage-landing globally visible.
#define BARWAIT()                                           \
    __builtin_amdgcn_s_barrier();                           \
    asm volatile("s_waitcnt lgkmcnt(0)" ::: "memory");      \
    __builtin_amdgcn_sched_barrier(0);                      \
    __builtin_amdgcn_s_setprio(1)
#define ENDPH()                                             \
    __builtin_amdgcn_s_setprio(0);                          \
    __builtin_amdgcn_s_barrier()

// =====================================================================
// GEMM1: zx[8192][4224] = A[8192][1024] * W[4224][1024]^T  (bf16 out)
// BM=256 x BN=192, BK=64, NT=16. 8 waves (2M x 4N), wave 128x48.
// 2 LDS buffers (112 KiB). 8 phases per 2 K-tiles, 12 MFMA/cluster.
// LDS layout (proven conflict-free): row-major [rows][64], 128B rows,
// chunk c of row r stored at chunk c ^ (r&7). Staged via linear gl_lds dest
// + per-lane pre-swizzled global source.
// Stage schedule (iter i, tiles T0=2i buf0 @P1-4, T1 buf1 @P5-8):
//   P1: T1.A (4 ld)      [buf1.A dead since prev P8]
//   P2/P3/P4: T2.B units [buf0.B dead after P1]
//   P5: T2.A (4 ld)      [buf0.A dead after P4]
//   P6/P7/P8: T3.B units [buf1.B dead after P5]
// Waits: vmcnt(3) before P4 and P8 barriers (allow 3 newest B stage-instrs).
// =====================================================================
__global__ __launch_bounds__(512, 2) void k_g1(const bf16* __restrict__ Ap,
                                               const bf16* __restrict__ Wp,
                                               bf16* __restrict__ Cp) {
    __shared__ __align__(16) short sA[2][16384];  // [buf][256][64]
    __shared__ __align__(16) short sB[2][12288];  // [buf][192][64]
    const int tid = threadIdx.x;
    const int lane = tid & 63, w = tid >> 6;
    const int wm = w >> 2, wn = w & 3;
    const int lr = lane & 15, lk = lane >> 4;
    int bx, by; swzx(bx, by);
    const int m0 = by * 256, n0 = bx * 192;
    const int ld = DMODEL;

    const int r8 = tid >> 3;
    const int c8 = ((tid & 7) ^ (r8 & 7)) * 8;
    const bf16* pA = Ap + (size_t)(m0 + r8) * ld + c8;
    const bf16* pB = Wp + (size_t)(n0 + r8) * ld + c8;

    auto stA = [&](int d, int t) {  // both 128-row halves, 4 load-instrs
#pragma unroll
        for (int h = 0; h < 2; h++)
#pragma unroll
            for (int q = 0; q < 2; q++)
                gl_lds16(pA + (size_t)(h * 128 + q * 64) * ld + t * 64,
                         (bf16*)&sA[d][h * 8192 + q * 4096 + tid * 8]);
    };
    auto stB = [&](int d, int u, int t) {  // one 64-row unit, 1 load-instr
        gl_lds16(pB + (size_t)(u * 64) * ld + t * 64,
                 (bf16*)&sB[d][u * 4096 + tid * 8]);
    };

    const int c0 = (lk ^ (lr & 7)) * 8;
    const int c1 = ((lk + 4) ^ (lr & 7)) * 8;
    const int aR = (wm * 128 + lr) * 64;
    const int bR = (wn * 48 + lr) * 64;

    f32x4 acc[8][3];
#pragma unroll
    for (int i = 0; i < 8; i++)
#pragma unroll
        for (int j = 0; j < 3; j++) acc[i][j] = (f32x4){0.f, 0.f, 0.f, 0.f};
    short8 bfr[3][2], af[2][2];

#define RDA1(D, I)                                                   \
    af[0][0] = *(const short8*)&sA[D][aR + (I) * 1024 + c0];         \
    af[0][1] = *(const short8*)&sA[D][aR + (I) * 1024 + c1];         \
    af[1][0] = *(const short8*)&sA[D][aR + (I + 1) * 1024 + c0];     \
    af[1][1] = *(const short8*)&sA[D][aR + (I + 1) * 1024 + c1]
#define RDB1(D)                                                      \
    _Pragma("unroll")                                                \
    for (int jn = 0; jn < 3; ++jn) {                                 \
        bfr[jn][0] = *(const short8*)&sB[D][bR + jn * 1024 + c0];    \
        bfr[jn][1] = *(const short8*)&sB[D][bR + jn * 1024 + c1];    \
    }
#define MM1(I)                                                       \
    _Pragma("unroll")                                                \
    for (int hh = 0; hh < 2; ++hh) {                                 \
        _Pragma("unroll")                                            \
        for (int jn = 0; jn < 3; ++jn) {                             \
            acc[I][jn]     = MF(af[0][hh], bfr[jn][hh], acc[I][jn]); \
            acc[I + 1][jn] = MF(af[1][hh], bfr[jn][hh], acc[I + 1][jn]); \
        }                                                            \
    }

    // prologue: T0 complete (7 instr) + T1.B (3 instr); allow T1.B in flight
    stB(0, 0, 0); stB(0, 1, 0); stB(0, 2, 0); stA(0, 0);
    stB(1, 0, 1); stB(1, 1, 1); stB(1, 2, 1);
    vmw<3>();
    __builtin_amdgcn_s_barrier();

    for (int t0 = 0; t0 < 16; t0 += 2) {
        const int t1 = t0 + 1, t2 = t0 + 2, t3 = t0 + 3;
        const bool more = (t2 < 16);
        // P1
        RDB1(0); RDA1(0, 0);
        stA(1, t1);
        BARWAIT(); MM1(0); ENDPH();
        // P2
        RDA1(0, 2); if (more) stB(0, 0, t2);
        BARWAIT(); MM1(2); ENDPH();
        // P3
        RDA1(0, 4); if (more) stB(0, 1, t2);
        BARWAIT(); MM1(4); ENDPH();
        // P4
        RDA1(0, 6); if (more) stB(0, 2, t2);
        BARWAIT(); MM1(6);
        __builtin_amdgcn_s_setprio(0);
        if (more) vmw<3>(); else vmw<0>();
        __builtin_amdgcn_s_barrier();
        // P5
        RDB1(1); RDA1(1, 0);
        if (more) stA(0, t2);
        BARWAIT(); MM1(0); ENDPH();
        // P6
        RDA1(1, 2); if (more) stB(1, 0, t3);
        BARWAIT(); MM1(2); ENDPH();
        // P7
        RDA1(1, 4); if (more) stB(1, 1, t3);
        BARWAIT(); MM1(4); ENDPH();
        // P8
        RDA1(1, 6); if (more) stB(1, 2, t3);
        BARWAIT(); MM1(6);
        __builtin_amdgcn_s_setprio(0);
        if (more) vmw<3>();
        __builtin_amdgcn_s_barrier();
    }
#undef RDA1
#undef RDB1
#undef MM1

#pragma unroll
    for (int im = 0; im < 8; im++) {
        int row = m0 + wm * 128 + im * 16 + lk * 4;
#pragma unroll
        for (int jn = 0; jn < 3; jn++) {
            int col = n0 + wn * 48 + jn * 16 + lr;
            bf16* cp = Cp + (size_t)row * N1 + col;
#pragma unroll
            for (int rr = 0; rr < 4; rr++) cp[(size_t)rr * N1] = __float2bfloat16(acc[im][jn][rr]);
        }
    }
}

// =====================================================================
// GEMM2 (+fused RMSNorm): out[8192][1024] = A(zx)[8192][2048] * W[1024][2048]^T
// BM=256 x BN=128, BK=64, NT=32. 8 waves (4M x 2N), wave 64x64.
// 3 LDS buffers (144 KiB): tile t in buf t%3; stage tile t+2 into buf (t+2)%3
// (= buffer freed when tile t-1 finished). 2 phases/tile, 16 MFMA/cluster.
// Single vmcnt(6) per tile before Pb's 2nd barrier (allow this tile's 6
// stage-instrs; forces tile-(t+1)'s stages landed). Grid 8x32=256, zero tail.
// =====================================================================
__global__ __launch_bounds__(512, 2) void k_g2(const bf16* __restrict__ Ap,
                                               const bf16* __restrict__ Wp,
                                               float* __restrict__ Cp) {
    __shared__ __align__(16) short sA[3][16384];  // [buf][256][64]
    __shared__ __align__(16) short sB[3][8192];   // [buf][128][64]
    __shared__ float rsrow[256];
    const int tid = threadIdx.x;
    const int lane = tid & 63, w = tid >> 6;
    const int wm = w >> 1, wn = w & 1;
    const int lr = lane & 15, lk = lane >> 4;
    int bx, by; swzx(bx, by);
    const int m0 = by * 256, n0 = bx * 128;
    const int lda = N1, ldb = DINNER;

    const int r8 = tid >> 3;
    const int c8 = ((tid & 7) ^ (r8 & 7)) * 8;
    const bf16* pA = Ap + (size_t)(m0 + r8) * lda + c8;
    const bf16* pB = Wp + (size_t)(n0 + r8) * ldb + c8;

    auto stA = [&](int d, int t) {  // 4 load-instrs
#pragma unroll
        for (int h = 0; h < 2; h++)
#pragma unroll
            for (int q = 0; q < 2; q++)
                gl_lds16(pA + (size_t)(h * 128 + q * 64) * lda + t * 64,
                         (bf16*)&sA[d][h * 8192 + q * 4096 + tid * 8]);
    };
    auto stB = [&](int d, int t) {  // 2 load-instrs
#pragma unroll
        for (int q = 0; q < 2; q++)
            gl_lds16(pB + (size_t)(q * 64) * ldb + t * 64,
                     (bf16*)&sB[d][q * 4096 + tid * 8]);
    };

    const int c0 = (lk ^ (lr & 7)) * 8;
    const int c1 = ((lk + 4) ^ (lr & 7)) * 8;
    const int aR = (wm * 64 + lr) * 64;
    const int bR = (wn * 64 + lr) * 64;

    f32x4 acc[4][4];
#pragma unroll
    for (int i = 0; i < 4; i++)
#pragma unroll
        for (int j = 0; j < 4; j++) acc[i][j] = (f32x4){0.f, 0.f, 0.f, 0.f};
    float ssq[4] = {0.f, 0.f, 0.f, 0.f};
    short8 bfr[4][2], af[2][2];

#define RDA2(D, I)                                                   \
    af[0][0] = *(const short8*)&sA[D][aR + (I) * 1024 + c0];         \
    af[0][1] = *(const short8*)&sA[D][aR + (I) * 1024 + c1];         \
    af[1][0] = *(const short8*)&sA[D][aR + (I + 1) * 1024 + c0];     \
    af[1][1] = *(const short8*)&sA[D][aR + (I + 1) * 1024 + c1]
#define RDB2(D)                                                      \
    _Pragma("unroll")                                                \
    for (int jn = 0; jn < 4; ++jn) {                                 \
        bfr[jn][0] = *(const short8*)&sB[D][bR + jn * 1024 + c0];    \
        bfr[jn][1] = *(const short8*)&sB[D][bR + jn * 1024 + c1];    \
    }
#define MM2(I)                                                       \
    _Pragma("unroll")                                                \
    for (int hh = 0; hh < 2; ++hh) {                                 \
        _Pragma("unroll")                                            \
        for (int jn = 0; jn < 4; ++jn) {                             \
            acc[I][jn]     = MF(af[0][hh], bfr[jn][hh], acc[I][jn]); \
            acc[I + 1][jn] = MF(af[1][hh], bfr[jn][hh], acc[I + 1][jn]); \
        }                                                            \
    }
#define SSQ2(I)                                                      \
    _Pragma("unroll")                                                \
    for (int hh = 0; hh < 2; ++hh)                                   \
        _Pragma("unroll")                                            \
        for (int e = 0; e < 8; ++e) {                                \
            float v0 = bits2f(af[0][hh][e]), v1 = bits2f(af[1][hh][e]); \
            ssq[I] += v0 * v0; ssq[I + 1] += v1 * v1;                \
        }

    // prologue: T0 (6 instr) then T1 (6 instr); allow T1 in flight
    stB(0, 0); stA(0, 0);
    stB(1, 1); stA(1, 1);
    vmw<6>();
    __builtin_amdgcn_s_barrier();

    int rb = 0, sb = 2;
    for (int t = 0; t < 32; ++t) {
        const bool more = (t + 2 < 32);
        // Pa: B full + A im0,1 (12 ds_reads), stage next B
        RDB2(rb); RDA2(rb, 0);
        if (more) stB(sb, t + 2);
        BARWAIT(); MM2(0); SSQ2(0); ENDPH();
        // Pb: A im2,3 (4 ds_reads), stage next A
        RDA2(rb, 2);
        if (more) stA(sb, t + 2);
        BARWAIT(); MM2(2); SSQ2(2);
        __builtin_amdgcn_s_setprio(0);
        if (more) vmw<6>(); else if (t + 1 < 32) vmw<0>();
        __builtin_amdgcn_s_barrier();
        rb = (rb == 2) ? 0 : rb + 1;
        sb = (sb == 2) ? 0 : sb + 1;
    }
#undef RDA2
#undef RDB2
#undef MM2
#undef SSQ2

    // ssq reduce over the 4 lk lanes holding the same row (lr fixed);
    // wn-duplicate waves write identical rsrow values (benign).
#pragma unroll
    for (int im = 0; im < 4; im++) {
        float s = ssq[im];
        s += __shfl_down(s, 32);
        s += __shfl_down(s, 16);
        if (lane < 16) rsrow[wm * 64 + im * 16 + lane] = rsqrtf(s * (1.0f / DINNER) + 1e-5f);
    }
    __syncthreads();
#pragma unroll
    for (int im = 0; im < 4; im++) {
        int rl = wm * 64 + im * 16 + lk * 4;
        int row = m0 + rl;
#pragma unroll
        for (int rr = 0; rr < 4; rr++) {
            float s = rsrow[rl + rr];
#pragma unroll
            for (int jn = 0; jn < 4; jn++) {
                int col = n0 + wn * 64 + jn * 16 + lr;
                Cp[(size_t)(row + rr) * DMODEL + col] = acc[im][jn][rr] * s;
            }
        }
    }
}

// ---------------- fused: u row -> bf16 + dt projection (dt stored [h][t]) ----------------
__global__ __launch_bounds__(256) void k_prep(const float* __restrict__ u, const float* __restrict__ W_in,
                                              const float* __restrict__ dt_bias,
                                              bf16* __restrict__ u_b, float* __restrict__ dtt) {
    __shared__ __align__(16) float us[8 * DMODEL];
    const int t0 = blockIdx.x * 8;
    const int tid = threadIdx.x;
    const float* ur = u + (size_t)t0 * DMODEL;
    bf16* ub = u_b + (size_t)t0 * DMODEL;
#pragma unroll
    for (int i = 0; i < 8; i++) {
        int idx = (i * 256 + tid) * 4;
        f32x4 v = *(const f32x4*)&ur[idx];
        *(f32x4*)&us[idx] = v;
        short4_ o;
#pragma unroll
        for (int j = 0; j < 4; j++) o[j] = f2bits(v[j]);
        *(short4_*)&ub[idx] = o;
    }
    __syncthreads();
    const int h = tid >> 3, sub = tid & 7;
    const float* wr = W_in + (size_t)(DPROJ - NH + h) * DMODEL;
    float s[8] = {};
    for (int k = sub * 4; k < DMODEL; k += 32) {
        f32x4 w4 = *(const f32x4*)&wr[k];
#pragma unroll
        for (int rr = 0; rr < 8; rr++) {
            const float* up = &us[rr * DMODEL + k];
            s[rr] += up[0] * w4[0] + up[1] * w4[1] + up[2] * w4[2] + up[3] * w4[3];
        }
    }
#pragma unroll
    for (int rr = 0; rr < 8; rr++) {
        s[rr] += __shfl_down(s[rr], 4, 8);
        s[rr] += __shfl_down(s[rr], 2, 8);
        s[rr] += __shfl_down(s[rr], 1, 8);
    }
    if (sub == 0) {
        float bh = dt_bias[h];
#pragma unroll
        for (int rr = 0; rr < 8; rr++) {
            float x = s[rr] + bh;
            dtt[(size_t)h * MTOT + t0 + rr] = (x > 20.f) ? x : log1pf(__expf(x));
        }
    }
}

// ---------------- depthwise causal conv (width 4) + bias + SiLU — 4 channels/thread ----------------
__global__ void k_conv(const bf16* __restrict__ zx, const float* __restrict__ cw,
                       const float* __restrict__ cb, bf16* __restrict__ xbc) {
    int g = (blockIdx.x * 256 + threadIdx.x) * 4;
    if (g >= MTOT * CONVD) return;
    int c0 = g % CONVD;
    int t = g / CONVD;
    int s = t & (SEQ - 1);
    const short* base = (const short*)(zx + (size_t)t * N1 + DINNER + c0);
    f32x4 w0 = *(const f32x4*)&cw[(c0 + 0) * 4];
    f32x4 w1 = *(const f32x4*)&cw[(c0 + 1) * 4];
    f32x4 w2 = *(const f32x4*)&cw[(c0 + 2) * 4];
    f32x4 w3 = *(const f32x4*)&cw[(c0 + 3) * 4];
    f32x4 a = *(const f32x4*)&cb[c0];
#pragma unroll
    for (int k = 0; k < 4; k++) {
        int st = s - 3 + k;
        if (st >= 0) {
            short4_ v = *(const short4_*)(base + (long)(k - 3) * N1);
            a[0] += bits2f(v[0]) * w0[k];
            a[1] += bits2f(v[1]) * w1[k];
            a[2] += bits2f(v[2]) * w2[k];
            a[3] += bits2f(v[3]) * w3[k];
        }
    }
    short4_ o;
#pragma unroll
    for (int j = 0; j < 4; j++) o[j] = f2bits(a[j] * sigmoidf_(a[j]));
    *(short4_*)&xbc[g] = o;
}

// ---------------- fused SSD scan: single barrier/chunk, parity double-buffered tiles ----------------
__global__ __launch_bounds__(256) void k_ssd(const bf16* __restrict__ xbc, const float* __restrict__ dtt,
                                             const float* __restrict__ A_log, const float* __restrict__ Dp,
                                             bf16* __restrict__ zx) {
    __shared__ __align__(16) short Ct[2][64 * YSTR];  // C [l][n]; own-wave rows reused as Y [l][p]
    __shared__ __align__(16) short Bt[2][64 * YSTR];  // B [s][n]
    __shared__ __align__(16) short Bn[2][64 * YSTR];  // B^T [n][l]
    __shared__ __align__(16) short Xt[2][32 * YSTR];  // X^T [p][l]
    __shared__ __align__(16) short Sb[2][32 * YSTR];  // state bf16 [p][n] at chunk start
    __shared__ __align__(16) short Gs[4 * 16 * YSTR]; // per-wave G
    __shared__ __align__(16) float Sf[32 * 68];       // running state fp32 [p][n]
    __shared__ __align__(16) float sdt2[2][64], sAc2[2][64], sf2[2][64];
    __shared__ float set2[2];

    const int ph = blockIdx.x, h = blockIdx.y, b = blockIdx.z;
    const int tid = threadIdx.x;
    const int lane = tid & 63, w = tid >> 6;
    const int lr = lane & 15, lk = lane >> 4;
    const float Ah = -__expf(A_log[h]);
    const float Dh = Dp[h];
    const int xcol = h * HD + ph * 32;

    const int lrow = tid >> 2, c0 = (tid & 3) * 16, px = (tid & 3) * 8;
    const int zl = 16 * w + (lane >> 2), zp = (lane & 3) * 8;

    short8 rC0, rC1, rB0, rB1, rX, rZ;
    float rdt;
    auto load_chunk = [&](int cc) {
        int rows0 = b * SEQ + cc * CKL;
        const short* rp = (const short*)(xbc + (size_t)(rows0 + lrow) * CONVD);
        rC0 = *(const short8*)&rp[DINNER + DSTATE + c0];
        rC1 = *(const short8*)&rp[DINNER + DSTATE + c0 + 8];
        rB0 = *(const short8*)&rp[DINNER + c0];
        rB1 = *(const short8*)&rp[DINNER + c0 + 8];
        rX  = *(const short8*)&rp[xcol + px];
        rZ  = *(const short8*)((const short*)zx + (size_t)(rows0 + zl) * N1 + xcol + zp);
        rdt = dtt[(size_t)h * MTOT + rows0 + lane];
    };
    auto scatter = [&](int buf) {
        *(short8*)&Ct[buf][lrow * YSTR + c0] = rC0;
        *(short8*)&Ct[buf][lrow * YSTR + c0 + 8] = rC1;
        *(short8*)&Bt[buf][lrow * YSTR + c0] = rB0;
        *(short8*)&Bt[buf][lrow * YSTR + c0 + 8] = rB1;
#pragma unroll
        for (int j = 0; j < 8; j++) {
            Bn[buf][(c0 + j) * YSTR + lrow] = rB0[j];
            Bn[buf][(c0 + 8 + j) * YSTR + lrow] = rB1[j];
            Xt[buf][(px + j) * YSTR + lrow] = rX[j];
        }
    };
    auto dtscan = [&](int buf) {
        if (tid < 64) {
            float dv = rdt;
            float v = Ah * dv;
#pragma unroll
            for (int d = 1; d < 64; d <<= 1) { float o = __shfl_up(v, d); if (tid >= d) v += o; }
            float tot = __shfl(v, 63);
            sdt2[buf][tid] = dv; sAc2[buf][tid] = v; sf2[buf][tid] = __expf(tot - v) * dv;
            if (tid == 63) set2[buf] = __expf(tot);
        }
    };

    for (int i = tid; i < 32 * 68; i += 256) Sf[i] = 0.f;
    for (int i = tid; i < 32 * YSTR; i += 256) Sb[0][i] = 0;
    load_chunk(0);
    scatter(0);
    dtscan(0);
    __syncthreads();

    for (int c = 0; c < NCH; c++) {
        const int par = c & 1, nb = par ^ 1;
        const int rows0 = b * SEQ + c * CKL;
        float etot = set2[par];
        short8 zcur = rZ;                 // z of chunk c (loaded last iteration / pre-loop)
        if (c + 1 < NCH) load_chunk(c + 1);

        short8 cf0 = *(const short8*)&Ct[par][(16 * w + lr) * YSTR + lk * 8];
        short8 cf1 = *(const short8*)&Ct[par][(16 * w + lr) * YSTR + 32 + lk * 8];
        // P1: Y_off = C * S0^T
        f32x4 acc[2];
#pragma unroll
        for (int t = 0; t < 2; t++) {
            short8 s0 = *(const short8*)&Sb[par][(16 * t + lr) * YSTR + lk * 8];
            short8 s1 = *(const short8*)&Sb[par][(16 * t + lr) * YSTR + 32 + lk * 8];
            acc[t] = __builtin_amdgcn_mfma_f32_16x16x32_bf16(cf0, s0, (f32x4){0.f, 0.f, 0.f, 0.f}, 0, 0, 0);
            acc[t] = __builtin_amdgcn_mfma_f32_16x16x32_bf16(cf1, s1, acc[t], 0, 0, 0);
        }
        float sAcl[4], el[4];
#pragma unroll
        for (int rr = 0; rr < 4; rr++) { sAcl[rr] = sAc2[par][16 * w + lk * 4 + rr]; el[rr] = __expf(sAcl[rr]); }
#pragma unroll
        for (int t = 0; t < 2; t++)
#pragma unroll
            for (int rr = 0; rr < 4; rr++) acc[t][rr] *= el[rr];
        // P2: G = C * B^T, mask/decay, wave-private LDS round-trip
        short* gw = Gs + w * 16 * YSTR;
#pragma unroll
        for (int t = 0; t < 4; t++) {
            short8 b0 = *(const short8*)&Bt[par][(16 * t + lr) * YSTR + lk * 8];
            short8 b1 = *(const short8*)&Bt[par][(16 * t + lr) * YSTR + 32 + lk * 8];
            f32x4 g = __builtin_amdgcn_mfma_f32_16x16x32_bf16(cf0, b0, (f32x4){0.f, 0.f, 0.f, 0.f}, 0, 0, 0);
            g = __builtin_amdgcn_mfma_f32_16x16x32_bf16(cf1, b1, g, 0, 0, 0);
            int s = 16 * t + lr;
            float sAcs = sAc2[par][s], dts = sdt2[par][s];
#pragma unroll
            for (int rr = 0; rr < 4; rr++) {
                int l = 16 * w + lk * 4 + rr;
                float v = (s <= l) ? g[rr] * __expf(sAcl[rr] - sAcs) * dts : 0.f;
                gw[(lk * 4 + rr) * YSTR + s] = f2bits(v);
            }
        }
        // P3: Y += G * X
        short8 gf0 = *(const short8*)&gw[lr * YSTR + lk * 8];
        short8 gf1 = *(const short8*)&gw[lr * YSTR + 32 + lk * 8];
#pragma unroll
        for (int t = 0; t < 2; t++) {
            short8 x0 = *(const short8*)&Xt[par][(16 * t + lr) * YSTR + lk * 8];
            short8 x1 = *(const short8*)&Xt[par][(16 * t + lr) * YSTR + 32 + lk * 8];
            acc[t] = __builtin_amdgcn_mfma_f32_16x16x32_bf16(gf0, x0, acc[t], 0, 0, 0);
            acc[t] = __builtin_amdgcn_mfma_f32_16x16x32_bf16(gf1, x1, acc[t], 0, 0, 0);
        }
        // P4: Snew = (Xt*sf) * Bn^T ; Sf = Sf*etot + Snew ; Sb[nb] = bf16(Sf)
        {
            int pw = w & 1, nh2 = w >> 1;
            short8 xt0 = *(const short8*)&Xt[par][(16 * pw + lr) * YSTR + lk * 8];
            short8 xt1 = *(const short8*)&Xt[par][(16 * pw + lr) * YSTR + 32 + lk * 8];
            f32x4 sa0 = *(const f32x4*)&sf2[par][lk * 8];
            f32x4 sa1 = *(const f32x4*)&sf2[par][lk * 8 + 4];
            f32x4 sb0 = *(const f32x4*)&sf2[par][32 + lk * 8];
            f32x4 sb1 = *(const f32x4*)&sf2[par][32 + lk * 8 + 4];
            short8 xd0, xd1;
#pragma unroll
            for (int j = 0; j < 4; j++) {
                xd0[j]     = f2bits(bits2f(xt0[j])     * sa0[j]);
                xd0[4 + j] = f2bits(bits2f(xt0[4 + j]) * sa1[j]);
                xd1[j]     = f2bits(bits2f(xt1[j])     * sb0[j]);
                xd1[4 + j] = f2bits(bits2f(xt1[4 + j]) * sb1[j]);
            }
#pragma unroll
            for (int j = 0; j < 2; j++) {
                int nt = 2 * nh2 + j;
                short8 b0 = *(const short8*)&Bn[par][(16 * nt + lr) * YSTR + lk * 8];
                short8 b1 = *(const short8*)&Bn[par][(16 * nt + lr) * YSTR + 32 + lk * 8];
                f32x4 sacc = __builtin_amdgcn_mfma_f32_16x16x32_bf16(xd0, b0, (f32x4){0.f, 0.f, 0.f, 0.f}, 0, 0, 0);
                sacc = __builtin_amdgcn_mfma_f32_16x16x32_bf16(xd1, b1, sacc, 0, 0, 0);
#pragma unroll
                for (int rr = 0; rr < 4; rr++) {
                    int n = 16 * nt + lr;
                    int p = 16 * pw + lk * 4 + rr;
                    float nv = Sf[p * 68 + n] * etot + sacc[rr];
                    Sf[p * 68 + n] = nv;
                    Sb[nb][p * YSTR + n] = f2bits(nv);
                }
            }
        }
        // Y epilogue (+D*x) into Ct[par]'s own wave rows; coalesced z-gate
#pragma unroll
        for (int t = 0; t < 2; t++) {
#pragma unroll
            for (int rr = 0; rr < 4; rr++) {
                int p = 16 * t + lr;
                int l = 16 * w + lk * 4 + rr;
                float y = acc[t][rr] + Dh * bits2f(Xt[par][p * YSTR + l]);
                Ct[par][l * YSTR + p] = f2bits(y);
            }
        }
        {
            short8 y8 = *(const short8*)&Ct[par][zl * YSTR + zp];
            short* zpp = (short*)zx + (size_t)(rows0 + zl) * N1 + xcol + zp;
            short8 o;
#pragma unroll
            for (int j = 0; j < 8; j++) {
                float z = bits2f(zcur[j]);
                o[j] = f2bits(bits2f(y8[j]) * (z * sigmoidf_(z)));
            }
            *(short8*)zpp = o;
        }
        // stage chunk c+1 (off critical path: independent of this chunk's compute)
        if (c + 1 < NCH) {
            scatter(nb);
            dtscan(nb);
        }
        __syncthreads();
    }
}

extern "C" void kernel_launch(void* const* d_in, const int* in_sizes, int n_in,
                              void* d_out, int out_size, void* d_ws, size_t ws_size,
                              hipStream_t stream) {
    const float* u       = (const float*)d_in[0];
    const float* W_in    = (const float*)d_in[1];
    const float* conv_w  = (const float*)d_in[2];
    const float* conv_b  = (const float*)d_in[3];
    const float* dt_bias = (const float*)d_in[4];
    const float* A_log   = (const float*)d_in[5];
    const float* Dp      = (const float*)d_in[6];
    const float* norm_w  = (const float*)d_in[7];
    const float* W_out   = (const float*)d_in[8];
    float* out = (float*)d_out;

    // Workspace layout (~108 MiB total):
    char* ws = (char*)d_ws;
    bf16* zx     = (bf16*)ws;  ws += (size_t)MTOT * N1 * 2;       // 69.2 MB
    bf16* xbc    = (bf16*)ws;  ws += (size_t)MTOT * CONVD * 2;    // 34 MB
    bf16* wout_b = (bf16*)ws;  ws += (size_t)DMODEL * DINNER * 2; // 4 MB
    float* dtt   = (float*)ws; ws += (size_t)NH * MTOT * 4;       // 1 MB, [h][t]

    // d_out (32 MiB) doubles as scratch for GEMM1 inputs only.
    bf16* u_b   = (bf16*)d_out;                                      // 16 MB
    bf16* win_b = (bf16*)((char*)d_out + (size_t)MTOT * DMODEL * 2); // 8.25 MB

    k_prep<<<MTOT / 8, 256, 0, stream>>>(u, W_in, dt_bias, u_b, dtt);
    k_cvt2<<<((N1 * DMODEL + DMODEL * DINNER) / 4 + 255) / 256, 256, 0, stream>>>(
        W_in, W_out, norm_w, win_b, wout_b);

    // GEMM1: 256x192 tiles, 8-phase counted-vmcnt pipeline
    k_g1<<<dim3(N1 / 192, MTOT / 256), 512, 0, stream>>>(u_b, win_b, zx);

    k_conv<<<(MTOT * CONVD / 4 + 255) / 256, 256, 0, stream>>>(zx, conv_w, conv_b, xbc);

    k_ssd<<<dim3(2, NH, BSZ), 256, 0, stream>>>(xbc, dtt, A_log, Dp, zx);

    // GEMM2 (+RMS): 256x128 tiles, 3-buffer counted-vmcnt pipeline, zero tail
    k_g2<<<dim3(DMODEL / 128, MTOT / 256), 512, 0, stream>>>(zx, wout_b, out);
}